// Round 1
// baseline (76.758 us; speedup 1.0000x reference)
//
#include <hip/hip_runtime.h>

// Problem constants (B=16384, D=1024, HARD_RATIO=0.3 -> K=4915)
constexpr int B_ROWS = 16384;
constexpr int DIM    = 1024;
constexpr int K_HARD = 4915;           // max(1, int(16384 * 0.3))
constexpr float MARGIN_POS = 0.1f;
constexpr float MARGIN_NEG = 0.8f;

// ---------------------------------------------------------------------------
// Kernel 1: rowwise dot products. One wave (64 lanes) per row; float4 loads.
// Writes sim_pos[row] to ws[0..B) and sim_neg[row] to ws[B..2B).
// ---------------------------------------------------------------------------
__global__ __launch_bounds__(256) void dot_kernel(
    const float4* __restrict__ q,
    const float4* __restrict__ dp,
    const float4* __restrict__ dn,
    float* __restrict__ out_pos,
    float* __restrict__ out_neg)
{
    const int wave = (blockIdx.x * blockDim.x + threadIdx.x) >> 6;
    const int lane = threadIdx.x & 63;
    if (wave >= B_ROWS) return;

    const int D4 = DIM / 4;                 // 256 float4 per row
    const size_t base = (size_t)wave * D4;

    float sp = 0.f, sn = 0.f;
#pragma unroll
    for (int it = 0; it < D4 / 64; ++it) {  // 4 iterations
        const int idx = it * 64 + lane;
        const float4 qv = q[base + idx];
        const float4 pv = dp[base + idx];
        const float4 nv = dn[base + idx];
        sp += qv.x * pv.x + qv.y * pv.y + qv.z * pv.z + qv.w * pv.w;
        sn += qv.x * nv.x + qv.y * nv.y + qv.z * nv.z + qv.w * nv.w;
    }
    // wave (64-lane) reduction
#pragma unroll
    for (int off = 32; off > 0; off >>= 1) {
        sp += __shfl_down(sp, off);
        sn += __shfl_down(sn, off);
    }
    if (lane == 0) {
        out_pos[wave] = sp;
        out_neg[wave] = sn;
    }
}

// order-preserving float -> uint32 key (ascending float == ascending uint)
__device__ __forceinline__ unsigned f2key(float f) {
    unsigned u = __float_as_uint(f);
    return (u & 0x80000000u) ? ~u : (u | 0x80000000u);
}
__device__ __forceinline__ float key2f(unsigned k) {
    return __uint_as_float((k & 0x80000000u) ? (k & 0x7FFFFFFFu) : ~k);
}

// ---------------------------------------------------------------------------
// Kernel 2: exact order-statistic via 4-round byte radix-select (MSB first),
// then conditional sum with tie correction. Block 0 = positives (k-th largest,
// f(v)=relu(v-0.1)); block 1 = negatives (k-th smallest, f(v)=relu(0.8-v)).
// Writes loss_pos -> loss_out[0], loss_neg -> loss_out[1].
// ---------------------------------------------------------------------------
__global__ __launch_bounds__(1024) void select_kernel(
    const float* __restrict__ vals_base,
    float* __restrict__ loss_out)
{
    const int N = B_ROWS;
    const bool isNeg = (blockIdx.x == 1);
    const float* vals = vals_base + (size_t)blockIdx.x * N;
    const int tid = threadIdx.x;

    // each thread holds 16 values in registers
    float v[16];
    unsigned key[16];
#pragma unroll
    for (int j = 0; j < 16; ++j) {
        float f = vals[tid + j * 1024];
        v[j] = f;
        key[j] = f2key(f);
    }

    // target 0-based ascending rank:
    //   pos: rank N-K  (smallest member of the top-K largest)
    //   neg: rank K-1  (largest member of the bottom-K smallest)
    unsigned m = isNeg ? (unsigned)(K_HARD - 1) : (unsigned)(N - K_HARD);

    __shared__ unsigned hist[256];
    __shared__ unsigned s_prefix, s_m;
    unsigned prefix = 0;

#pragma unroll
    for (int r = 0; r < 4; ++r) {
        if (tid < 256) hist[tid] = 0;
        __syncthreads();
        const unsigned shift = 24 - 8 * r;
        const unsigned prefmask = (r == 0) ? 0u : (0xFFFFFFFFu << (32 - 8 * r));
#pragma unroll
        for (int j = 0; j < 16; ++j) {
            if ((key[j] & prefmask) == prefix)
                atomicAdd(&hist[(key[j] >> shift) & 255u], 1u);
        }
        __syncthreads();
        if (tid == 0) {
            unsigned cum = 0, b = 0;
            for (; b < 256u; ++b) {
                if (cum + hist[b] > m) break;
                cum += hist[b];
            }
            s_prefix = prefix | (b << shift);
            s_m = m - cum;
        }
        __syncthreads();
        prefix = s_prefix;
        m = s_m;
        __syncthreads();
    }

    const unsigned tkey = prefix;            // exact k-th order statistic (bits)
    const float    tval = key2f(tkey);

    // conditional sum over strictly-beyond-threshold values
    float lsum = 0.f;
    unsigned cnt = 0;
#pragma unroll
    for (int j = 0; j < 16; ++j) {
        if (!isNeg) {
            if (key[j] > tkey) { lsum += fmaxf(v[j] - MARGIN_POS, 0.f); cnt++; }
        } else {
            if (key[j] < tkey) { lsum += fmaxf(MARGIN_NEG - v[j], 0.f); cnt++; }
        }
    }

    // deterministic block tree-reduction
    __shared__ float    redf[1024];
    __shared__ unsigned redi[1024];
    redf[tid] = lsum;
    redi[tid] = cnt;
    __syncthreads();
#pragma unroll
    for (int s = 512; s > 0; s >>= 1) {
        if (tid < s) {
            redf[tid] += redf[tid + s];
            redi[tid] += redi[tid + s];
        }
        __syncthreads();
    }

    if (tid == 0) {
        const float ft = isNeg ? fmaxf(MARGIN_NEG - tval, 0.f)
                               : fmaxf(tval - MARGIN_POS, 0.f);
        const float total = redf[0] + (float)(K_HARD - (int)redi[0]) * ft;
        loss_out[blockIdx.x] = total / (float)K_HARD;
    }
}

// ---------------------------------------------------------------------------
// Kernel 3: combine. out = (loss_pos + loss_neg, loss_pos, loss_neg)
// ---------------------------------------------------------------------------
__global__ void finalize_kernel(const float* __restrict__ losses,
                                float* __restrict__ out)
{
    const float lp = losses[0];
    const float ln = losses[1];
    out[0] = lp + ln;
    out[1] = lp;
    out[2] = ln;
}

extern "C" void kernel_launch(void* const* d_in, const int* in_sizes, int n_in,
                              void* d_out, int out_size, void* d_ws, size_t ws_size,
                              hipStream_t stream) {
    const float4* q  = (const float4*)d_in[0];   // q_neg_proj
    const float4* dp = (const float4*)d_in[1];   // d_pos
    const float4* dn = (const float4*)d_in[2];   // d_neg
    float* out = (float*)d_out;                  // 3 floats

    float* ws      = (float*)d_ws;
    float* ws_pos  = ws;                 // [0, B)
    float* ws_neg  = ws + B_ROWS;        // [B, 2B)
    float* ws_loss = ws + 2 * B_ROWS;    // [2B, 2B+2)

    // Kernel 1: one wave per row -> B waves -> B*64 threads, 256/block
    {
        const int threads = 256;
        const int blocks = (B_ROWS * 64) / threads;   // 4096
        dot_kernel<<<blocks, threads, 0, stream>>>(q, dp, dn, ws_pos, ws_neg);
    }
    // Kernel 2: block 0 = pos, block 1 = neg
    select_kernel<<<2, 1024, 0, stream>>>(ws_pos, ws_loss);
    // Kernel 3: combine
    finalize_kernel<<<1, 1, 0, stream>>>(ws_loss, out);
}

// Round 2
// 55.514 us; speedup vs baseline: 1.3827x; 1.3827x over previous
//
#include <hip/hip_runtime.h>

// Problem constants (B=16384, D=1024, HARD_RATIO=0.3 -> K=4915)
constexpr int B_ROWS = 16384;
constexpr int K_HARD = 4915;           // max(1, int(16384 * 0.3))
constexpr float MARGIN_POS = 0.1f;
constexpr float MARGIN_NEG = 0.8f;

// ---------------------------------------------------------------------------
// Kernel 1: rowwise dot products. One wave per row; all 12 float4 loads
// issued before any FMA (max memory parallelism); VGPR<=64 via
// __launch_bounds__(256,8) keeps 8 waves/SIMD resident -> ~6KB in flight/CU.
// ---------------------------------------------------------------------------
__global__ __launch_bounds__(256, 8) void dot_kernel(
    const float4* __restrict__ q,
    const float4* __restrict__ dp,
    const float4* __restrict__ dn,
    float* __restrict__ out_pos,
    float* __restrict__ out_neg)
{
    const int wave = (blockIdx.x * blockDim.x + threadIdx.x) >> 6;
    const int lane = threadIdx.x & 63;
    const int base = wave * 256 + lane;     // float4 index; chunk stride 64

    float4 qv[4], pv[4], nv[4];
#pragma unroll
    for (int it = 0; it < 4; ++it) qv[it] = q[base + it * 64];
#pragma unroll
    for (int it = 0; it < 4; ++it) pv[it] = dp[base + it * 64];
#pragma unroll
    for (int it = 0; it < 4; ++it) nv[it] = dn[base + it * 64];

    float sp = 0.f, sn = 0.f;
#pragma unroll
    for (int it = 0; it < 4; ++it) {
        sp += qv[it].x * pv[it].x + qv[it].y * pv[it].y
            + qv[it].z * pv[it].z + qv[it].w * pv[it].w;
        sn += qv[it].x * nv[it].x + qv[it].y * nv[it].y
            + qv[it].z * nv[it].z + qv[it].w * nv[it].w;
    }
#pragma unroll
    for (int off = 32; off; off >>= 1) {
        sp += __shfl_xor(sp, off);
        sn += __shfl_xor(sn, off);
    }
    if (lane == 0) {
        out_pos[wave] = sp;
        out_neg[wave] = sn;
    }
}

// order-preserving float -> uint32 key (ascending float == ascending uint)
__device__ __forceinline__ unsigned f2key(float f) {
    unsigned u = __float_as_uint(f);
    return (u & 0x80000000u) ? ~u : (u | 0x80000000u);
}
__device__ __forceinline__ float key2f(unsigned k) {
    return __uint_as_float((k & 0x80000000u) ? (k & 0x7FFFFFFFu) : ~k);
}

// ---------------------------------------------------------------------------
// Kernel 2 (fused select + finalize): one 1024-thread block does BOTH sides
// sequentially. Exact k-th order statistic via 4-round byte radix-select with
// a wave-parallel bucket scan (no serial 256-iter loop), then conditional sum
// with tie correction. Writes all 3 outputs.
// ---------------------------------------------------------------------------
__global__ __launch_bounds__(1024) void select_finalize_kernel(
    const float* __restrict__ ws_vals,   // [2*B]: pos then neg
    float* __restrict__ out)             // 3 floats
{
    __shared__ unsigned hist[256];
    __shared__ unsigned ebase[256];      // exclusive prefix per bin
    __shared__ unsigned s_prefix, s_m;
    __shared__ float    s_redf[16];
    __shared__ int      s_redc[16];
    __shared__ float    s_loss[2];

    const int tid  = threadIdx.x;
    const int lane = tid & 63;
    const int wid  = tid >> 6;

    for (int side = 0; side < 2; ++side) {
        const float4* v4 = (const float4*)(ws_vals + side * B_ROWS);

        // 16 values per thread, loaded as 4x float4 (coalesced)
        unsigned key[16];
#pragma unroll
        for (int j = 0; j < 4; ++j) {
            float4 x = v4[tid + j * 1024];
            key[4 * j + 0] = f2key(x.x);
            key[4 * j + 1] = f2key(x.y);
            key[4 * j + 2] = f2key(x.z);
            key[4 * j + 3] = f2key(x.w);
        }

        // target 0-based ascending rank:
        //   pos (side 0): rank N-K (smallest member of top-K largest)
        //   neg (side 1): rank K-1 (largest member of bottom-K smallest)
        unsigned m = side ? (unsigned)(K_HARD - 1) : (unsigned)(B_ROWS - K_HARD);
        unsigned prefix = 0;

        for (int r = 0; r < 4; ++r) {
            const unsigned shift = 24 - 8 * r;
            const unsigned pmask = (r == 0) ? 0u : (0xFFFFFFFFu << (32 - 8 * r));
            if (tid < 256) hist[tid] = 0;
            __syncthreads();
#pragma unroll
            for (int j = 0; j < 16; ++j)
                if ((key[j] & pmask) == prefix)
                    atomicAdd(&hist[(key[j] >> shift) & 255u], 1u);
            __syncthreads();

            // wave 0: parallel exclusive prefix over 256 bins (4 bins/lane)
            if (wid == 0) {
                unsigned h0 = hist[4 * lane + 0];
                unsigned h1 = hist[4 * lane + 1];
                unsigned h2 = hist[4 * lane + 2];
                unsigned h3 = hist[4 * lane + 3];
                unsigned gsum = h0 + h1 + h2 + h3;
                unsigned inc = gsum;
#pragma unroll
                for (int off = 1; off < 64; off <<= 1) {
                    unsigned t = __shfl_up(inc, off);
                    if (lane >= off) inc += t;
                }
                unsigned ex = inc - gsum;
                ebase[4 * lane + 0] = ex;
                ebase[4 * lane + 1] = ex + h0;
                ebase[4 * lane + 2] = ex + h0 + h1;
                ebase[4 * lane + 3] = ex + h0 + h1 + h2;
            }
            __syncthreads();

            if (tid < 256) {
                unsigned lo = ebase[tid];
                unsigned hi = lo + hist[tid];
                if (lo <= m && m < hi) {     // exactly one bucket satisfies
                    s_prefix = prefix | ((unsigned)tid << shift);
                    s_m = m - lo;
                }
            }
            __syncthreads();
            prefix = s_prefix;
            m = s_m;
            // safe: next writes to hist/s_prefix occur only after 2 more syncs
        }

        const unsigned tkey = prefix;        // exact k-th order statistic bits
        const float    tval = key2f(tkey);

        // conditional sum over strictly-beyond-threshold values
        float lsum = 0.f;
        int cnt = 0;
#pragma unroll
        for (int j = 0; j < 16; ++j) {
            const bool sel = side ? (key[j] < tkey) : (key[j] > tkey);
            if (sel) {
                const float v = key2f(key[j]);
                lsum += side ? fmaxf(MARGIN_NEG - v, 0.f)
                             : fmaxf(v - MARGIN_POS, 0.f);
                cnt++;
            }
        }
#pragma unroll
        for (int off = 32; off; off >>= 1) {
            lsum += __shfl_xor(lsum, off);
            cnt  += __shfl_xor(cnt, off);
        }
        if (lane == 0) { s_redf[wid] = lsum; s_redc[wid] = cnt; }
        __syncthreads();
        if (tid == 0) {
            float tot = 0.f;
            int c = 0;
            for (int w = 0; w < 16; ++w) { tot += s_redf[w]; c += s_redc[w]; }
            const float ft = side ? fmaxf(MARGIN_NEG - tval, 0.f)
                                  : fmaxf(tval - MARGIN_POS, 0.f);
            s_loss[side] = (tot + (float)(K_HARD - c) * ft) / (float)K_HARD;
        }
        __syncthreads();
    }

    if (tid == 0) {
        const float lp = s_loss[0];
        const float ln = s_loss[1];
        out[0] = lp + ln;
        out[1] = lp;
        out[2] = ln;
    }
}

extern "C" void kernel_launch(void* const* d_in, const int* in_sizes, int n_in,
                              void* d_out, int out_size, void* d_ws, size_t ws_size,
                              hipStream_t stream) {
    const float4* q  = (const float4*)d_in[0];   // q_neg_proj
    const float4* dp = (const float4*)d_in[1];   // d_pos
    const float4* dn = (const float4*)d_in[2];   // d_neg
    float* out = (float*)d_out;                  // 3 floats

    float* ws     = (float*)d_ws;
    float* ws_pos = ws;                // [0, B)
    float* ws_neg = ws + B_ROWS;       // [B, 2B)

    // Kernel 1: one wave per row -> 16384 waves -> 4096 blocks x 256
    dot_kernel<<<(B_ROWS * 64) / 256, 256, 0, stream>>>(q, dp, dn, ws_pos, ws_neg);
    // Kernel 2: single block, both sides + finalize
    select_finalize_kernel<<<1, 1024, 0, stream>>>(ws_pos, out);
}

// Round 3
// 52.792 us; speedup vs baseline: 1.4540x; 1.0515x over previous
//
#include <hip/hip_runtime.h>

// Problem constants (B=16384, D=1024, HARD_RATIO=0.3 -> K=4915)
constexpr int B_ROWS = 16384;
constexpr int K_HARD = 4915;           // max(1, int(16384 * 0.3))
constexpr float MARGIN_POS = 0.1f;
constexpr float MARGIN_NEG = 0.8f;

typedef float f32x4 __attribute__((ext_vector_type(4)));

// ---------------------------------------------------------------------------
// Kernel 1: rowwise dot products. One wave per row. All 12 global_load_dwordx4
// forced into flight via inline asm (earlyclobber outs -> 48 live VGPRs), one
// s_waitcnt vmcnt(0), then FMAs. Row = wave*4096B; chunks at +0/1024/2048/3072
// (13-bit imm offset). __launch_bounds__(256,8): 8 waves/SIMD resident.
// ---------------------------------------------------------------------------
__global__ __launch_bounds__(256, 8) void dot_kernel(
    const float* __restrict__ q,
    const float* __restrict__ dp,
    const float* __restrict__ dn,
    float* __restrict__ out_pos,
    float* __restrict__ out_neg)
{
    const int wave = (blockIdx.x * blockDim.x + threadIdx.x) >> 6;
    const int lane = threadIdx.x & 63;
    const unsigned voff = (unsigned)wave * 4096u + (unsigned)lane * 16u;

    f32x4 q0, q1, q2, q3, p0, p1, p2, p3, n0, n1, n2, n3;
    asm volatile(
        "global_load_dwordx4 %[Q0], %[VO], %[QB] offset:0\n\t"
        "global_load_dwordx4 %[Q1], %[VO], %[QB] offset:1024\n\t"
        "global_load_dwordx4 %[Q2], %[VO], %[QB] offset:2048\n\t"
        "global_load_dwordx4 %[Q3], %[VO], %[QB] offset:3072\n\t"
        "global_load_dwordx4 %[P0], %[VO], %[PB] offset:0\n\t"
        "global_load_dwordx4 %[P1], %[VO], %[PB] offset:1024\n\t"
        "global_load_dwordx4 %[P2], %[VO], %[PB] offset:2048\n\t"
        "global_load_dwordx4 %[P3], %[VO], %[PB] offset:3072\n\t"
        "global_load_dwordx4 %[N0], %[VO], %[NB] offset:0\n\t"
        "global_load_dwordx4 %[N1], %[VO], %[NB] offset:1024\n\t"
        "global_load_dwordx4 %[N2], %[VO], %[NB] offset:2048\n\t"
        "global_load_dwordx4 %[N3], %[VO], %[NB] offset:3072\n\t"
        "s_waitcnt vmcnt(0)"
        : [Q0]"=&v"(q0), [Q1]"=&v"(q1), [Q2]"=&v"(q2), [Q3]"=&v"(q3),
          [P0]"=&v"(p0), [P1]"=&v"(p1), [P2]"=&v"(p2), [P3]"=&v"(p3),
          [N0]"=&v"(n0), [N1]"=&v"(n1), [N2]"=&v"(n2), [N3]"=&v"(n3)
        : [VO]"v"(voff), [QB]"s"(q), [PB]"s"(dp), [NB]"s"(dn)
    );

    f32x4 qa[4] = {q0, q1, q2, q3};
    f32x4 pa[4] = {p0, p1, p2, p3};
    f32x4 na[4] = {n0, n1, n2, n3};

    float sp = 0.f, sn = 0.f;
#pragma unroll
    for (int it = 0; it < 4; ++it) {
#pragma unroll
        for (int c = 0; c < 4; ++c) {
            sp += qa[it][c] * pa[it][c];
            sn += qa[it][c] * na[it][c];
        }
    }
#pragma unroll
    for (int off = 32; off; off >>= 1) {
        sp += __shfl_xor(sp, off);
        sn += __shfl_xor(sn, off);
    }
    if (lane == 0) {
        out_pos[wave] = sp;
        out_neg[wave] = sn;
    }
}

// order-preserving float -> uint32 key (ascending float == ascending uint)
__device__ __forceinline__ unsigned f2key(float f) {
    unsigned u = __float_as_uint(f);
    return (u & 0x80000000u) ? ~u : (u | 0x80000000u);
}
__device__ __forceinline__ float key2f(unsigned k) {
    return __uint_as_float((k & 0x80000000u) ? (k & 0x7FFFFFFFu) : ~k);
}

// ---------------------------------------------------------------------------
// Kernel 2 (fused select + finalize): one 1024-thread block processes BOTH
// sides CONCURRENTLY (16 pos + 16 neg keys per thread, dual LDS histograms;
// wave 0 scans pos bins while wave 1 scans neg bins). Exact k-th order
// statistic via 4-round byte radix-select, then conditional sum with tie
// correction. Writes all 3 outputs.
// ---------------------------------------------------------------------------
__global__ __launch_bounds__(1024) void select_finalize_kernel(
    const float* __restrict__ ws_vals,   // [2*B]: pos then neg
    float* __restrict__ out)             // 3 floats
{
    __shared__ unsigned hist[2][256];
    __shared__ unsigned ebase[2][256];
    __shared__ unsigned s_prefix[2], s_m[2];
    __shared__ float    s_rf[2][16];
    __shared__ unsigned s_rc[2][16];

    const int tid  = threadIdx.x;
    const int lane = tid & 63;
    const int wid  = tid >> 6;

    const float4* vp = (const float4*)ws_vals;              // pos
    const float4* vn = (const float4*)(ws_vals + B_ROWS);   // neg

    unsigned kp[16], kn[16];
#pragma unroll
    for (int j = 0; j < 4; ++j) {
        const float4 a = vp[tid + j * 1024];
        const float4 b = vn[tid + j * 1024];
        kp[4*j+0] = f2key(a.x); kp[4*j+1] = f2key(a.y);
        kp[4*j+2] = f2key(a.z); kp[4*j+3] = f2key(a.w);
        kn[4*j+0] = f2key(b.x); kn[4*j+1] = f2key(b.y);
        kn[4*j+2] = f2key(b.z); kn[4*j+3] = f2key(b.w);
    }

    // target 0-based ascending ranks:
    //   pos: rank N-K (smallest member of top-K largest)
    //   neg: rank K-1 (largest member of bottom-K smallest)
    unsigned m0 = (unsigned)(B_ROWS - K_HARD), pre0 = 0;
    unsigned m1 = (unsigned)(K_HARD - 1),      pre1 = 0;

    for (int r = 0; r < 4; ++r) {
        const unsigned shift = 24 - 8 * r;
        const unsigned pmask = (r == 0) ? 0u : (0xFFFFFFFFu << (32 - 8 * r));
        if (tid < 256) { hist[0][tid] = 0; hist[1][tid] = 0; }
        __syncthreads();
#pragma unroll
        for (int j = 0; j < 16; ++j) {
            if ((kp[j] & pmask) == pre0) atomicAdd(&hist[0][(kp[j] >> shift) & 255u], 1u);
            if ((kn[j] & pmask) == pre1) atomicAdd(&hist[1][(kn[j] >> shift) & 255u], 1u);
        }
        __syncthreads();

        // wave 0 scans side 0, wave 1 scans side 1 (4 bins/lane, shfl_up scan)
        if (wid < 2) {
            const int s = wid;
            const unsigned h0 = hist[s][4*lane+0], h1 = hist[s][4*lane+1];
            const unsigned h2 = hist[s][4*lane+2], h3 = hist[s][4*lane+3];
            const unsigned g = h0 + h1 + h2 + h3;
            unsigned inc = g;
#pragma unroll
            for (int off = 1; off < 64; off <<= 1) {
                const unsigned t = __shfl_up(inc, off);
                if (lane >= off) inc += t;
            }
            const unsigned ex = inc - g;
            ebase[s][4*lane+0] = ex;
            ebase[s][4*lane+1] = ex + h0;
            ebase[s][4*lane+2] = ex + h0 + h1;
            ebase[s][4*lane+3] = ex + h0 + h1 + h2;
        }
        __syncthreads();

        if (tid < 512) {
            const int s = tid >> 8;
            const int b = tid & 255;
            const unsigned mm = s ? m1 : m0;
            const unsigned lo = ebase[s][b];
            const unsigned hi = lo + hist[s][b];
            if (lo <= mm && mm < hi) {      // exactly one bucket per side
                s_prefix[s] = (s ? pre1 : pre0) | ((unsigned)b << shift);
                s_m[s] = mm - lo;
            }
        }
        __syncthreads();
        pre0 = s_prefix[0]; m0 = s_m[0];
        pre1 = s_prefix[1]; m1 = s_m[1];
        // safe: hist/s_prefix next written only after 2+ more syncs
    }

    const unsigned tk0 = pre0, tk1 = pre1;   // exact k-th order statistics
    const float    tv0 = key2f(tk0), tv1 = key2f(tk1);

    float lp = 0.f, ln = 0.f;
    unsigned cp = 0, cn = 0;
#pragma unroll
    for (int j = 0; j < 16; ++j) {
        if (kp[j] > tk0) { lp += fmaxf(key2f(kp[j]) - MARGIN_POS, 0.f); cp++; }
        if (kn[j] < tk1) { ln += fmaxf(MARGIN_NEG - key2f(kn[j]), 0.f); cn++; }
    }
#pragma unroll
    for (int off = 32; off; off >>= 1) {
        lp += __shfl_xor(lp, off);  ln += __shfl_xor(ln, off);
        cp += __shfl_xor(cp, off);  cn += __shfl_xor(cn, off);
    }
    if (lane == 0) {
        s_rf[0][wid] = lp; s_rf[1][wid] = ln;
        s_rc[0][wid] = cp; s_rc[1][wid] = cn;
    }
    __syncthreads();
    if (tid == 0) {
        float tp = 0.f, tn = 0.f;
        unsigned ccp = 0, ccn = 0;
        for (int w = 0; w < 16; ++w) {
            tp += s_rf[0][w]; tn += s_rf[1][w];
            ccp += s_rc[0][w]; ccn += s_rc[1][w];
        }
        const float fp = fmaxf(tv0 - MARGIN_POS, 0.f);
        const float fn = fmaxf(MARGIN_NEG - tv1, 0.f);
        const float LP = (tp + (float)(K_HARD - (int)ccp) * fp) / (float)K_HARD;
        const float LN = (tn + (float)(K_HARD - (int)ccn) * fn) / (float)K_HARD;
        out[0] = LP + LN;
        out[1] = LP;
        out[2] = LN;
    }
}

extern "C" void kernel_launch(void* const* d_in, const int* in_sizes, int n_in,
                              void* d_out, int out_size, void* d_ws, size_t ws_size,
                              hipStream_t stream) {
    const float* q  = (const float*)d_in[0];   // q_neg_proj
    const float* dp = (const float*)d_in[1];   // d_pos
    const float* dn = (const float*)d_in[2];   // d_neg
    float* out = (float*)d_out;                // 3 floats

    float* ws     = (float*)d_ws;
    float* ws_pos = ws;                // [0, B)
    float* ws_neg = ws + B_ROWS;       // [B, 2B)

    // Kernel 1: one wave per row -> 16384 waves -> 4096 blocks x 256
    dot_kernel<<<(B_ROWS * 64) / 256, 256, 0, stream>>>(q, dp, dn, ws_pos, ws_neg);
    // Kernel 2: single block, both sides concurrently + finalize
    select_finalize_kernel<<<1, 1024, 0, stream>>>(ws_pos, out);
}